// Round 8
// baseline (374.162 us; speedup 1.0000x reference)
//
#include <hip/hip_runtime.h>
#include <hip/hip_fp16.h>

// LightGCN 3-layer propagation. out layout: [4, N_NODES, DIM] f32.
//   layer 0 = embeddings (copy); layer l = SpMM(layer l-1).
//
// Ledger:
//  R4-R8: scatter fight. ranges(blockIdx%8)+NT loads = best (WRITE 54.6 MB,
//      64us); write-amp beyond that is structural. Atomic rule: per-address
//      returning-atomic multiplicity must stay <= tens (R5: 410ns/op serial).
//  R8: hex spmm (16 chains) < oct (8 chains) -> spmm not latency-bound.
//  R10: fp16-mirror spmm: 393->366, absmax 0.25. Only ~9us/layer saved ->
//      spmm NOT byte-bound; bound by random-gather service point. x_h=12.8MB
//      >> 4MB/XCD L2 -> ~30% L2 hit, rest L3/IF at ~1.5-2 TB/s random rate.
//  R11 (this round): src-range-ordered CSR. Edge order within a node's
//      segment is free; sort by src-range (16 ranges, ~1MB fp16 tile each)
//      via per-(dst,range) counters (1.6M, mult ~0.75) + 1.6M scan. All waves
//      sweep ranges in the same sequence -> instantaneous gather working set
//      ~2-3MB -> L2-resident. spmm kernel itself UNCHANGED (risk-free order).

#define N_NODES 100000
#define DIM 64
#define SCAN_CHUNK 1024

#define NR 8                              // dst ranges for scatter (XCD rr)
#define RSIZE ((N_NODES + NR - 1) / NR)   // 12500 nodes per dst range
#define SLICES 128                        // edge slices per dst range

#define NRG 16                            // src ranges (gather tiles)
#define RNG_SH 13                         // src>>13 -> range 0..12 (8192/range)
#define NG (N_NODES * NRG)                // 1.6M (dst,range) counters

typedef int   vint4   __attribute__((ext_vector_type(4)));
typedef float vfloat4 __attribute__((ext_vector_type(4)));

union HU { unsigned u; __half2 h; };

// ---------------- layer 0: copy f32 + build fp16 mirror ----------------
__global__ void convert_kernel(const float* __restrict__ emb, float* __restrict__ out0,
                               unsigned short* __restrict__ xh0, int n8) {
    int i = blockIdx.x * blockDim.x + threadIdx.x;   // 8 floats per thread
    if (i >= n8) return;
    const vfloat4* e4 = (const vfloat4*)emb;
    vfloat4 a = __builtin_nontemporal_load(e4 + 2 * i);
    vfloat4 b = __builtin_nontemporal_load(e4 + 2 * i + 1);
    vfloat4* o4 = (vfloat4*)out0;
    __builtin_nontemporal_store(a, o4 + 2 * i);
    __builtin_nontemporal_store(b, o4 + 2 * i + 1);
    HU c0, c1, c2, c3;
    c0.h = __float22half2_rn(make_float2(a[0], a[1]));
    c1.h = __float22half2_rn(make_float2(a[2], a[3]));
    c2.h = __float22half2_rn(make_float2(b[0], b[1]));
    c3.h = __float22half2_rn(make_float2(b[2], b[3]));
    vint4 p = { (int)c0.u, (int)c1.u, (int)c2.u, (int)c3.u };
    ((vint4*)xh0)[i] = p;
}

// ---------------- CSR build, src-range-ordered ----------------

// (dst,src-range) histogram: 1.2M atomics over 1.6M counters (mult ~0.75).
__global__ void hist2_kernel(const int* __restrict__ esrc, const int* __restrict__ edst,
                             int* __restrict__ h2, int E) {
    int i = blockIdx.x * blockDim.x + threadIdx.x;
    int nv = E >> 2;
    if (i < nv) {
        vint4 d = __builtin_nontemporal_load(((const vint4*)edst) + i);
        vint4 s = __builtin_nontemporal_load(((const vint4*)esrc) + i);
        #pragma unroll
        for (int j = 0; j < 4; ++j)
            atomicAdd(&h2[d[j] * NRG + (s[j] >> RNG_SH)], 1);
    }
    if (i == 0) {
        for (int e = nv << 2; e < E; ++e)
            atomicAdd(&h2[edst[e] * NRG + (esrc[e] >> RNG_SH)], 1);
    }
}

// Per-block exclusive scan over chunks of 1024; emits per-block totals.
__global__ void scan1_kernel(const int* __restrict__ src, int* __restrict__ dst,
                             int* __restrict__ bsum, int n) {
    __shared__ int sdata[256];
    int tid = threadIdx.x;
    int base = blockIdx.x * SCAN_CHUNK + tid * 4;
    int v[4];
    #pragma unroll
    for (int i = 0; i < 4; ++i) v[i] = (base + i < n) ? src[base + i] : 0;
    int tsum = v[0] + v[1] + v[2] + v[3];
    sdata[tid] = tsum;
    __syncthreads();
    for (int d = 1; d < 256; d <<= 1) {
        int t = (tid >= d) ? sdata[tid - d] : 0;
        __syncthreads();
        sdata[tid] += t;
        __syncthreads();
    }
    int excl = sdata[tid] - tsum;
    if (tid == 255) bsum[blockIdx.x] = sdata[255];
    int run = excl;
    #pragma unroll
    for (int i = 0; i < 4; ++i) {
        if (base + i < n) dst[base + i] = run;
        run += v[i];
    }
}

// Single-block exclusive scan of up to 2048 block sums (1024 thr x 2).
__global__ void scan2b_kernel(int* __restrict__ bsum, int nb) {
    __shared__ int s[1024];
    int t = threadIdx.x;
    int i0 = 2 * t, i1 = 2 * t + 1;
    int v0 = (i0 < nb) ? bsum[i0] : 0;
    int v1 = (i1 < nb) ? bsum[i1] : 0;
    s[t] = v0 + v1;
    __syncthreads();
    for (int d = 1; d < 1024; d <<= 1) {
        int tt = (t >= d) ? s[t - d] : 0;
        __syncthreads();
        s[t] += tt;
        __syncthreads();
    }
    int excl = s[t] - (v0 + v1);
    if (i0 < nb) bsum[i0] = excl;
    if (i1 < nb) bsum[i1] = excl + v0;
}

// Finalize pos2, seed cur2, and emit node offsets (off[d] = pos2[d*NRG]).
__global__ void scan3b_kernel(int* __restrict__ pos2, int* __restrict__ cur2,
                              int* __restrict__ off, const int* __restrict__ bsum, int n) {
    int i = blockIdx.x * blockDim.x + threadIdx.x;
    if (i < n) {
        int v = pos2[i] + bsum[i >> 10];
        pos2[i] = v;
        cur2[i] = v;
        if ((i & (NRG - 1)) == 0) off[i / NRG] = v;
    }
}

__global__ void deg_kernel(const int* __restrict__ off, int* __restrict__ deg,
                           int E, int n) {
    int i = blockIdx.x * blockDim.x + threadIdx.x;
    if (i < n) deg[i] = ((i == n - 1) ? E : off[i + 1]) - off[i];
}

// R6-proven scatter (dst-range partitioned + NT streams), now placing each
// edge at its (dst, src-range) slot -> node segments sorted by src-range.
__global__ void scatter_range_kernel(const int* __restrict__ esrc, const int* __restrict__ edst,
                                     const float* __restrict__ ew, int* __restrict__ cur2,
                                     int2* __restrict__ pairs, int E, int chunk) {
    const int r = blockIdx.x & (NR - 1);
    const int s = blockIdx.x / NR;
    const int lo = r * RSIZE;
    const int hi = min(lo + RSIZE, N_NODES);
    const int e0 = s * chunk;
    if (e0 >= E) return;
    const int e1 = min(e0 + chunk, E);
    const int nv = (e1 - e0) >> 2;
    const vint4*   s4 = (const vint4*)(esrc + e0);
    const vint4*   d4 = (const vint4*)(edst + e0);
    const vfloat4* w4 = (const vfloat4*)(ew + e0);
    for (int i = threadIdx.x; i < nv; i += blockDim.x) {
        vint4 dd = __builtin_nontemporal_load(d4 + i);
        vint4 ss = __builtin_nontemporal_load(s4 + i);
        vfloat4 ww = __builtin_nontemporal_load(w4 + i);
        #pragma unroll
        for (int j = 0; j < 4; ++j) {
            int dj = dd[j];
            if (dj >= lo && dj < hi) {
                int p = atomicAdd(&cur2[dj * NRG + (ss[j] >> RNG_SH)], 1);
                int2 pr;
                pr.x = ss[j];
                pr.y = __float_as_int(ww[j]);
                pairs[p] = pr;
            }
        }
    }
    for (int e = e0 + (nv << 2) + threadIdx.x; e < e1; e += blockDim.x) {
        int dj = edst[e];
        if (dj >= lo && dj < hi) {
            int p = atomicAdd(&cur2[dj * NRG + (esrc[e] >> RNG_SH)], 1);
            int2 pr;
            pr.x = esrc[e];
            pr.y = __float_as_int(ew[e]);
            pairs[p] = pr;
        }
    }
}

// ---------------- SpMM fp16-gather: one wave per node, oct scheme ----------
// UNCHANGED from R10 (the ordering win comes from the pairs layout).

__global__ void spmm_h_kernel(const unsigned short* __restrict__ xh,
                              const int2* __restrict__ pairs,
                              const int* __restrict__ off,
                              const int* __restrict__ deg,
                              float* __restrict__ y,
                              unsigned short* __restrict__ yh) {
    int gtid = blockIdx.x * blockDim.x + threadIdx.x;
    int node = gtid >> 6;
    int lane = threadIdx.x & 63;
    int o  = lane >> 3;
    int ol = lane & 7;
    if (node >= N_NODES) return;
    int s0 = off[node];
    int n  = deg[node];
    float a0 = 0.f, a1 = 0.f, a2 = 0.f, a3 = 0.f;
    float a4 = 0.f, a5 = 0.f, a6 = 0.f, a7 = 0.f;   // dims [8ol, 8ol+8)
    for (int k = o; k < n; k += 8) {
        int2 pr = pairs[s0 + k];                     // uniform within oct
        float w = __int_as_float(pr.y);
        const vint4* row = (const vint4*)(xh + (size_t)pr.x * DIM);
        vint4 v = row[ol];                           // 8 lanes x 16 B = 128 B row
        HU c; float2 f;
        c.u = (unsigned)v[0]; f = __half22float2(c.h); a0 += w * f.x; a1 += w * f.y;
        c.u = (unsigned)v[1]; f = __half22float2(c.h); a2 += w * f.x; a3 += w * f.y;
        c.u = (unsigned)v[2]; f = __half22float2(c.h); a4 += w * f.x; a5 += w * f.y;
        c.u = (unsigned)v[3]; f = __half22float2(c.h); a6 += w * f.x; a7 += w * f.y;
    }
    #pragma unroll
    for (int d = 8; d <= 32; d <<= 1) {
        a0 += __shfl_xor(a0, d); a1 += __shfl_xor(a1, d);
        a2 += __shfl_xor(a2, d); a3 += __shfl_xor(a3, d);
        a4 += __shfl_xor(a4, d); a5 += __shfl_xor(a5, d);
        a6 += __shfl_xor(a6, d); a7 += __shfl_xor(a7, d);
    }
    if (o == 0) {
        float* yr = y + (size_t)node * DIM + ol * 8;
        vfloat4 r0 = { a0, a1, a2, a3 };
        vfloat4 r1 = { a4, a5, a6, a7 };
        __builtin_nontemporal_store(r0, (vfloat4*)yr);
        __builtin_nontemporal_store(r1, (vfloat4*)yr + 1);
        HU c0, c1, c2, c3;
        c0.h = __float22half2_rn(make_float2(a0, a1));
        c1.h = __float22half2_rn(make_float2(a2, a3));
        c2.h = __float22half2_rn(make_float2(a4, a5));
        c3.h = __float22half2_rn(make_float2(a6, a7));
        vint4 p = { (int)c0.u, (int)c1.u, (int)c2.u, (int)c3.u };
        *((vint4*)(yh + (size_t)node * DIM + ol * 8)) = p;
    }
}

// ---------------- legacy kernels for fallback paths ----------------

__global__ void hist_kernel(const int* __restrict__ edst, int* __restrict__ deg, int E) {
    int i = blockIdx.x * blockDim.x + threadIdx.x;
    int nv = E >> 2;
    if (i < nv) {
        vint4 d = __builtin_nontemporal_load(((const vint4*)edst) + i);
        atomicAdd(&deg[d[0]], 1);
        atomicAdd(&deg[d[1]], 1);
        atomicAdd(&deg[d[2]], 1);
        atomicAdd(&deg[d[3]], 1);
    }
    if (i == 0) {
        for (int e = nv << 2; e < E; ++e) atomicAdd(&deg[edst[e]], 1);
    }
}

__global__ void scan3_kernel(int* __restrict__ off, int* __restrict__ cur,
                             const int* __restrict__ bsum, int n) {
    int i = blockIdx.x * blockDim.x + threadIdx.x;
    if (i < n) {
        int v = off[i] + bsum[i / SCAN_CHUNK];
        off[i] = v;
        cur[i] = v;
    }
}

__global__ void scatter_range1_kernel(const int* __restrict__ esrc, const int* __restrict__ edst,
                                      const float* __restrict__ ew, int* __restrict__ cur,
                                      int2* __restrict__ pairs, int E, int chunk) {
    const int r = blockIdx.x & (NR - 1);
    const int s = blockIdx.x / NR;
    const int lo = r * RSIZE;
    const int hi = min(lo + RSIZE, N_NODES);
    const int e0 = s * chunk;
    if (e0 >= E) return;
    const int e1 = min(e0 + chunk, E);
    const int nv = (e1 - e0) >> 2;
    const vint4*   s4 = (const vint4*)(esrc + e0);
    const vint4*   d4 = (const vint4*)(edst + e0);
    const vfloat4* w4 = (const vfloat4*)(ew + e0);
    for (int i = threadIdx.x; i < nv; i += blockDim.x) {
        vint4 dd = __builtin_nontemporal_load(d4 + i);
        vint4 ss = __builtin_nontemporal_load(s4 + i);
        vfloat4 ww = __builtin_nontemporal_load(w4 + i);
        #pragma unroll
        for (int j = 0; j < 4; ++j) {
            int dj = dd[j];
            if (dj >= lo && dj < hi) {
                int p = atomicAdd(&cur[dj], 1);
                int2 pr;
                pr.x = ss[j];
                pr.y = __float_as_int(ww[j]);
                pairs[p] = pr;
            }
        }
    }
    for (int e = e0 + (nv << 2) + threadIdx.x; e < e1; e += blockDim.x) {
        int dj = edst[e];
        if (dj >= lo && dj < hi) {
            int p = atomicAdd(&cur[dj], 1);
            int2 pr;
            pr.x = esrc[e];
            pr.y = __float_as_int(ew[e]);
            pairs[p] = pr;
        }
    }
}

__global__ void spmm_csr_kernel(const float* __restrict__ x,
                                const int2* __restrict__ pairs,
                                const int* __restrict__ off,
                                const int* __restrict__ deg,
                                float* __restrict__ y) {
    int gtid = blockIdx.x * blockDim.x + threadIdx.x;
    int node = gtid >> 6;
    int lane = threadIdx.x & 63;
    int o  = lane >> 3;
    int ol = lane & 7;
    if (node >= N_NODES) return;
    int s0 = off[node];
    int n  = deg[node];
    float4 a0 = make_float4(0.f, 0.f, 0.f, 0.f);
    float4 a1 = a0;
    for (int k = o; k < n; k += 8) {
        int2 pr = pairs[s0 + k];
        float w = __int_as_float(pr.y);
        const float4* row = (const float4*)(x + (size_t)pr.x * DIM);
        float4 v0 = row[ol];
        float4 v1 = row[ol + 8];
        a0.x += w * v0.x; a0.y += w * v0.y; a0.z += w * v0.z; a0.w += w * v0.w;
        a1.x += w * v1.x; a1.y += w * v1.y; a1.z += w * v1.z; a1.w += w * v1.w;
    }
    #pragma unroll
    for (int d = 8; d <= 32; d <<= 1) {
        a0.x += __shfl_xor(a0.x, d); a0.y += __shfl_xor(a0.y, d);
        a0.z += __shfl_xor(a0.z, d); a0.w += __shfl_xor(a0.w, d);
        a1.x += __shfl_xor(a1.x, d); a1.y += __shfl_xor(a1.y, d);
        a1.z += __shfl_xor(a1.z, d); a1.w += __shfl_xor(a1.w, d);
    }
    if (o == 0) {
        vfloat4* yrow = (vfloat4*)(y + (size_t)node * DIM);
        vfloat4 r0 = { a0.x, a0.y, a0.z, a0.w };
        vfloat4 r1 = { a1.x, a1.y, a1.z, a1.w };
        __builtin_nontemporal_store(r0, yrow + ol);
        __builtin_nontemporal_store(r1, yrow + ol + 8);
    }
}

__global__ void spmm_atomic_kernel(const float* __restrict__ x, const float* __restrict__ ew,
                                   const int* __restrict__ esrc, const int* __restrict__ edst,
                                   float* __restrict__ y, int n_edges) {
    long long tid = (long long)blockIdx.x * blockDim.x + threadIdx.x;
    int e = (int)(tid >> 6);
    int d = (int)(tid & 63);
    if (e >= n_edges) return;
    int s = esrc[e]; int t = edst[e]; float w = ew[e];
    atomicAdd(&y[(long long)t * DIM + d], w * x[(long long)s * DIM + d]);
}

extern "C" void kernel_launch(void* const* d_in, const int* in_sizes, int n_in,
                              void* d_out, int out_size, void* d_ws, size_t ws_size,
                              hipStream_t stream) {
    const float* emb  = (const float*)d_in[0];
    const float* ew   = (const float*)d_in[1];
    const int*   esrc = (const int*)d_in[2];
    const int*   edst = (const int*)d_in[3];
    float* out = (float*)d_out;

    const int E = in_sizes[1];
    const size_t layer_elems = (size_t)N_NODES * DIM;

    const size_t need_srt = (size_t)E * 8 + 2 * layer_elems * 2
                          + (size_t)3 * NG * 4 + (size_t)2 * N_NODES * 4 + 16384;
    const size_t need_h   = (size_t)E * 8 + 2 * layer_elems * 2 + (size_t)3 * N_NODES * 4 + 1024;
    const size_t need_f32 = (size_t)E * 8 + (size_t)3 * N_NODES * 4 + 1024;

    if (ws_size >= need_srt && E >= 4) {
        char* w = (char*)d_ws;
        int2* pairs = (int2*)w;
        unsigned short* xh0 = (unsigned short*)(w + (size_t)E * 8);
        unsigned short* xh1 = xh0 + layer_elems;
        int* h2   = (int*)(xh1 + layer_elems);
        int* pos2 = h2 + NG;
        int* cur2 = pos2 + NG;
        int* off  = cur2 + NG;
        int* deg  = off + N_NODES;
        int* bsum = deg + N_NODES;      // 2048 ints

        hipMemsetAsync(h2, 0, (size_t)NG * 4, stream);

        const int n8 = (int)(layer_elems / 8);
        convert_kernel<<<(n8 + 255) / 256, 256, 0, stream>>>(emb, out, xh0, n8);

        const int nv4 = E >> 2;
        hist2_kernel<<<(nv4 + 255) / 256, 256, 0, stream>>>(esrc, edst, h2, E);

        const int nscan = (NG + SCAN_CHUNK - 1) / SCAN_CHUNK;   // 1563
        scan1_kernel<<<nscan, 256, 0, stream>>>(h2, pos2, bsum, NG);
        scan2b_kernel<<<1, 1024, 0, stream>>>(bsum, nscan);
        scan3b_kernel<<<(NG + 255) / 256, 256, 0, stream>>>(pos2, cur2, off, bsum, NG);
        deg_kernel<<<(N_NODES + 255) / 256, 256, 0, stream>>>(off, deg, E, N_NODES);

        const int chunk = (((E + SLICES - 1) / SLICES) + 3) & ~3;
        scatter_range_kernel<<<NR * SLICES, 256, 0, stream>>>(esrc, edst, ew, cur2, pairs, E, chunk);

        const int nb = (N_NODES + 3) / 4;   // 4 waves (nodes) per 256-thread block
        unsigned short* xs[2] = { xh0, xh1 };
        for (int l = 1; l <= 3; ++l) {
            spmm_h_kernel<<<nb, 256, 0, stream>>>(
                xs[(l - 1) & 1], pairs, off, deg,
                out + (size_t)l * layer_elems, xs[l & 1]);
        }
    } else if (ws_size >= need_h && E >= 4) {
        // R10 path: fp16 mirror, node-level counters only.
        char* w = (char*)d_ws;
        int2* pairs = (int2*)w;
        unsigned short* xh0 = (unsigned short*)(w + (size_t)E * 8);
        unsigned short* xh1 = xh0 + layer_elems;
        int* deg  = (int*)(xh1 + layer_elems);
        int* cur  = deg + N_NODES;
        int* off  = cur + N_NODES;
        int* bsum = off + N_NODES;

        hipMemsetAsync(deg, 0, (size_t)N_NODES * 4, stream);
        const int n8 = (int)(layer_elems / 8);
        convert_kernel<<<(n8 + 255) / 256, 256, 0, stream>>>(emb, out, xh0, n8);
        const int nv4 = E >> 2;
        hist_kernel<<<(nv4 + 255) / 256, 256, 0, stream>>>(edst, deg, E);
        const int nscan = (N_NODES + SCAN_CHUNK - 1) / SCAN_CHUNK;
        scan1_kernel<<<nscan, 256, 0, stream>>>(deg, off, bsum, N_NODES);
        scan2b_kernel<<<1, 1024, 0, stream>>>(bsum, nscan);
        scan3_kernel<<<(N_NODES + 255) / 256, 256, 0, stream>>>(off, cur, bsum, N_NODES);
        const int chunk = (((E + SLICES - 1) / SLICES) + 3) & ~3;
        scatter_range1_kernel<<<NR * SLICES, 256, 0, stream>>>(esrc, edst, ew, cur, pairs, E, chunk);
        const int nb = (N_NODES + 3) / 4;
        unsigned short* xs[2] = { xh0, xh1 };
        for (int l = 1; l <= 3; ++l) {
            spmm_h_kernel<<<nb, 256, 0, stream>>>(
                xs[(l - 1) & 1], pairs, off, deg,
                out + (size_t)l * layer_elems, xs[l & 1]);
        }
    } else if (ws_size >= need_f32 && E >= 4) {
        char* w = (char*)d_ws;
        int2* pairs = (int2*)w;
        int* deg  = (int*)(w + (size_t)E * 8);
        int* cur  = deg + N_NODES;
        int* off  = cur + N_NODES;
        int* bsum = off + N_NODES;

        hipMemcpyAsync(out, emb, layer_elems * sizeof(float), hipMemcpyDeviceToDevice, stream);
        hipMemsetAsync(deg, 0, (size_t)N_NODES * 4, stream);
        const int nv4 = E >> 2;
        hist_kernel<<<(nv4 + 255) / 256, 256, 0, stream>>>(edst, deg, E);
        const int nscan = (N_NODES + SCAN_CHUNK - 1) / SCAN_CHUNK;
        scan1_kernel<<<nscan, 256, 0, stream>>>(deg, off, bsum, N_NODES);
        scan2b_kernel<<<1, 1024, 0, stream>>>(bsum, nscan);
        scan3_kernel<<<(N_NODES + 255) / 256, 256, 0, stream>>>(off, cur, bsum, N_NODES);
        const int chunk = (((E + SLICES - 1) / SLICES) + 3) & ~3;
        scatter_range1_kernel<<<NR * SLICES, 256, 0, stream>>>(esrc, edst, ew, cur, pairs, E, chunk);
        const int nb = (N_NODES + 3) / 4;
        for (int l = 1; l <= 3; ++l) {
            spmm_csr_kernel<<<nb, 256, 0, stream>>>(
                out + (size_t)(l - 1) * layer_elems, pairs, off, deg,
                out + (size_t)l * layer_elems);
        }
    } else {
        hipMemcpyAsync(out, emb, layer_elems * sizeof(float), hipMemcpyDeviceToDevice, stream);
        hipMemsetAsync(out + layer_elems, 0, 3 * layer_elems * sizeof(float), stream);
        const long long total_threads = (long long)E * 64;
        const int blocks = (int)((total_threads + 255) / 256);
        for (int l = 1; l <= 3; ++l) {
            spmm_atomic_kernel<<<blocks, 256, 0, stream>>>(
                out + (size_t)(l - 1) * layer_elems, ew, esrc, edst,
                out + (size_t)l * layer_elems, E);
        }
    }
}